// Round 11
// baseline (181.646 us; speedup 1.0000x reference)
//
#include <hip/hip_runtime.h>
#include <math.h>

#define Bn 16
#define Ln 2048
#define Gn 8
#define Pn 8
#define Kn 64
#define CLAMP_V 15.0f

#define BPB 32              // blocks per batch
#define NTH 512             // threads per block = 8 waves
#define NWV (NTH / 64)      // 8 waves
#define LPB (Ln / BPB)      // 64 l's per block
#define LPW (LPB / NWV)     // 8 l's per wave
#define PK  (Pn * Kn)       // 512 ints per group table
#define WLCAP 128           // worklist capacity (E[entries]=16, 128 >> mean+10sd)

typedef unsigned long long ull;

// part[Gn][Bn][BPB][Pn] qwords: {MAGIC(g)<<32 | f32 partial}. Harness 0xAA
// poison never matches a tag -> the tagged partial IS the arrival signal.
#define MAGIC(g) (0x5EED0000u | (unsigned)(g))

// wave64 sum via DPP (VALU pipe). Total valid in lane 63 (and aliases).
__device__ __forceinline__ float wave_sum64(float x) {
#define DPP_ADD(ctrl) \
    x += __int_as_float(__builtin_amdgcn_update_dpp(0, __float_as_int(x), ctrl, 0xf, 0xf, true))
    DPP_ADD(0x111); DPP_ADD(0x112); DPP_ADD(0x114);
    DPP_ADD(0x118); DPP_ADD(0x142); DPP_ADD(0x143);
#undef DPP_ADD
    return x;
}

template <int IMM>
__device__ __forceinline__ float swz_xor(float v) {
    return v + __int_as_float(__builtin_amdgcn_ds_swizzle(__float_as_int(v), IMM));
}

// fold s_part[8 waves][8 p] in wave 0; lanes 0..7 hold the per-p totals.
// (round-9/10-validated mapping: lane = (q<<3)|p, fold q bits 0,1 via
// ds_swizzle xor, q bit 2 via cross-half shfl)
__device__ __forceinline__ float fold8x8(const float (*sp)[Pn], int lane) {
    float v = sp[lane >> 3][lane & 7];
    v = swz_xor<0x201F>(v);
    v = swz_xor<0x401F>(v);
    v += __shfl(v, lane + 32, 64);
    return v;
}

__device__ __forceinline__ ull ld_rlx64(const ull* p) {
    return __hip_atomic_load(p, __ATOMIC_RELAXED, __HIP_MEMORY_SCOPE_AGENT);
}
__device__ __forceinline__ void st_rlx64(ull* p, ull v) {
    __hip_atomic_store(p, v, __ATOMIC_RELAXED, __HIP_MEMORY_SCOPE_AGENT);
}

__device__ __forceinline__ float dp2_f(float px, float py, float pz, float4 q) {
    const float dx = px - q.x, dy = py - q.y, dz = pz - q.z;
    return dx * dx + dy * dy + dz * dz;
}
// shared by spec + both correction paths -> bitwise-identical terms cancel.
__device__ __forceinline__ float term2(float dp2, float nx, float ny, float nz, float4 m) {
    const float ex = nx - m.x, ey = ny - m.y, ez = nz - m.z;
    const float dn2 = ex * ex + ey * ey + ez * ez;
    const float s = __builtin_amdgcn_sqrtf(dp2 * dn2);
    return fminf((dp2 + dn2) - 2.0f * s, CLAMP_V);
}

// ---------------------------------------------------------------------------
// Speculative pipeline: iteration g computes group g+1's partials with the
// PRE-update-g map (2.5us), which hides the publish->observe latency+skew of
// group g's partials; after polling P_g and applying update g, an exact
// correction (worklist of changed lane-constants + changed-column sweeps)
// repairs S_{g+1}, which is then published. Serial chain per group shrinks
// from ~4.4us (round 10) to poll-hit + update + ~0.5us correction.
// ---------------------------------------------------------------------------
__global__ __launch_bounds__(NTH, 4) void fused_kernel(
    const float* __restrict__ xpred, const float* __restrict__ xnat,
    const int* __restrict__ mask_in, const int* __restrict__ autom,
    float* __restrict__ out_x, float* __restrict__ out_m,
    ull* __restrict__ part) {

    const int tid  = threadIdx.x;
    const int lane = tid & 63;       // k
    const int wv   = tid >> 6;       // wave 0..7
    const int b    = blockIdx.x >> 5;
    const int c    = blockIdx.x & (BPB - 1);

    __shared__ unsigned short s_idx[Ln];     // private permutation
    __shared__ signed char    s_stamp[Ln];   // last group that updated row
    __shared__ float4         s_xp[LPB];     // x_pred columns (static)
    __shared__ float4         s_xn[LPB];     // x_nat columns (map-after-(g-1))
    __shared__ float          s_part[NWV][Pn];
    __shared__ float          s_delta[Pn];   // worklist correction sums
    __shared__ float4         s_wl_m[WLCAP]; // {px,py,pz, bitcast(p)}
    __shared__ float4         s_wl_o[WLCAP]; // n_old
    __shared__ float4         s_wl_v[WLCAP]; // n_new
    __shared__ int            s_wl_cnt;
    __shared__ ull            s_chm;         // changed block-columns (update g)
    __shared__ ull            s_bmask[2];    // base-set mask per group parity

    const float* xpb = xpred + (size_t)b * Ln * 3;
    const float* xnb = xnat  + (size_t)b * Ln * 3;

    // ---- prologue ----
    for (int l = tid; l < Ln; l += NTH) { s_idx[l] = (unsigned short)l; s_stamp[l] = -1; }
    if (wv == 0) {
        const int l = c * LPB + lane;
        s_xp[lane] = make_float4(xpb[l*3], xpb[l*3+1], xpb[l*3+2], 0.0f);
    } else if (wv == 1) {
        const int l = c * LPB + lane;
        s_xn[lane] = make_float4(xnb[l*3], xnb[l*3+1], xnb[l*3+2], 0.0f);
    } else if (wv == 2) {
        if (lane == 0) { s_bmask[0] = 0ull; s_bmask[1] = 0ull; s_wl_cnt = 0; }
        // in-wave DS program order: zero (lane0's ds_write) precedes the ors
        const int a0 = autom[lane];            // group 0 base
        const int r0 = a0 - c * LPB;
        if (r0 >= 0 && r0 < LPB) atomicOr(&s_bmask[0], 1ull << r0);
        const int a1 = autom[PK + lane];       // group 1 base
        const int r1 = a1 - c * LPB;
        if (r1 >= 0 && r1 < LPB) atomicOr(&s_bmask[1], 1ull << r1);
    }
    int   a0k = autom[lane];                   // group 0 constants (identity map)
    float px = xpb[a0k*3], py = xpb[a0k*3+1], pz = xpb[a0k*3+2];
    float nx[Pn], ny[Pn], nz[Pn];
    #pragma unroll
    for (int p = 0; p < Pn; p++) {
        const int col = autom[p * Kn + lane];
        nx[p] = xnb[col*3]; ny[p] = xnb[col*3+1]; nz[p] = xnb[col*3+2];
    }
    __syncthreads();

    // ---- compute + publish P0 (no prior update -> exact, no correction) ----
    {
        const ull bm = s_bmask[0];
        float acc[Pn];
        #pragma unroll
        for (int p = 0; p < Pn; p++) acc[p] = 0.0f;
        const int il0 = wv * LPW;
        #pragma unroll 2
        for (int i = 0; i < LPW; i++) {
            const int il = il0 + i;
            if ((bm >> il) & 1) continue;
            const float4 q = s_xp[il], m = s_xn[il];
            const float dp2 = dp2_f(px, py, pz, q);
            #pragma unroll
            for (int p = 0; p < Pn; p++) acc[p] += term2(dp2, nx[p], ny[p], nz[p], m);
        }
        #pragma unroll
        for (int p = 0; p < Pn; p++) {
            const float v = wave_sum64(acc[p]);
            if (lane == 63) s_part[wv][p] = v;
        }
    }
    __syncthreads();
    if (wv == 0) {
        const float v = fold8x8(s_part, lane);
        if (lane < 8)
            st_rlx64(part + (size_t)(0 * Bn + b) * BPB * Pn + c * Pn + lane,
                     ((ull)MAGIC(0) << 32) | (ull)__float_as_uint(v));
    }
    // stage spec constants for group 1 (map is still identity)
    a0k = autom[PK + lane];
    px = xpb[a0k*3]; py = xpb[a0k*3+1]; pz = xpb[a0k*3+2];
    #pragma unroll
    for (int p = 0; p < Pn; p++) {
        const int col = autom[PK + p * Kn + lane];
        nx[p] = xnb[col*3]; ny[p] = xnb[col*3+1]; nz[p] = xnb[col*3+2];
    }
    __syncthreads();   // prologue fold consumed s_part before loop re-writes it

    #pragma unroll 1
    for (int g = 0; g < Gn; g++) {
        const bool hn  = (g < Gn - 1);
        const int* ag  = autom + g * PK;
        const int* ag1 = autom + (g + 1) * PK;            // used only if hn
        ull* pg = part + (size_t)(g * Bn + b) * BPB * Pn;
        const ull bm = hn ? s_bmask[(g + 1) & 1] : 0ull;
        float sreg = 0.0f;

        // ---- speculative compute of S_{g+1} (pre-update-g state) ----
        if (hn) {
            float acc[Pn];
            #pragma unroll
            for (int p = 0; p < Pn; p++) acc[p] = 0.0f;
            const int il0 = wv * LPW;
            #pragma unroll 2
            for (int i = 0; i < LPW; i++) {
                const int il = il0 + i;
                if ((bm >> il) & 1) continue;
                const float4 q = s_xp[il], m = s_xn[il];
                const float dp2 = dp2_f(px, py, pz, q);
                #pragma unroll
                for (int p = 0; p < Pn; p++) acc[p] += term2(dp2, nx[p], ny[p], nz[p], m);
            }
            #pragma unroll
            for (int p = 0; p < Pn; p++) {
                const float v = wave_sum64(acc[p]);
                if (lane == 63) s_part[wv][p] = v;
            }
        }
        __syncthreads();   // (A) s_part ready; prev iteration fully consumed

        if (wv == 0 && hn) sreg = fold8x8(s_part, lane);   // S in lanes 0..7
        if (wv == 1) {     // zero correction accumulators for this iteration
            if (lane < 8) s_delta[lane] = 0.0f;
            if (lane == 8) s_wl_cnt = 0;
        }
        if (wv == 0) {
            // ---- poll P_g (published one spec-compute ago -> usually hits) ----
            const unsigned magic = MAGIC(g);
            ull q0 = 0, q1 = 0, q2 = 0, q3 = 0;
            bool r0 = false, r1 = false, r2 = false, r3 = false;
            for (;;) {
                if (!r0) { q0 = ld_rlx64(pg + lane);       r0 = (unsigned)(q0 >> 32) == magic; }
                if (!r1) { q1 = ld_rlx64(pg + lane + 64);  r1 = (unsigned)(q1 >> 32) == magic; }
                if (!r2) { q2 = ld_rlx64(pg + lane + 128); r2 = (unsigned)(q2 >> 32) == magic; }
                if (!r3) { q3 = ld_rlx64(pg + lane + 192); r3 = (unsigned)(q3 >> 32) == magic; }
                if (__ballot(!(r0 && r1 && r2 && r3)) == 0ull) break;
                __builtin_amdgcn_s_sleep(1);
            }
            float v = __uint_as_float((unsigned)q0) + __uint_as_float((unsigned)q1)
                    + __uint_as_float((unsigned)q2) + __uint_as_float((unsigned)q3);
            v = swz_xor<0x201F>(v);
            v = swz_xor<0x401F>(v);
            v += __shfl(v, lane + 32, 64);
            float best = __shfl(v, 0, 64);
            int   bj   = 0;
            #pragma unroll
            for (int p = 1; p < Pn; p++) {
                const float t = __shfl(v, p, 64);
                if (t < best) { best = t; bj = p; }   // strict < == argmin tie rule
            }
            // apply update g (gather then scatter, in-wave DS order)
            const unsigned short oldv = s_idx[ag[bj * Kn + lane]];
            s_idx[ag[lane]]   = oldv;
            s_stamp[ag[lane]] = (signed char)g;
            const ull chm_l = __ballot(s_stamp[c * LPB + lane] == (signed char)g);
            if (lane == 0) s_chm = chm_l;
        }
        __syncthreads();   // (B) s_idx/stamp/chm visible; s_delta zeroed

        // ---- corrections for S_{g+1} ----
        if (hn) {
            const ull chm = s_chm;
            float d[Pn];
            #pragma unroll
            for (int p = 0; p < Pn; p++) d[p] = 0.0f;
            unsigned chp = 0;   // this lane's changed-constant p's
            #pragma unroll
            for (int p = 0; p < Pn; p++) {
                const int col = ag1[p * Kn + lane];
                if (s_stamp[col] == (signed char)g) {
                    chp |= 1u << p;
                    if (wv == 0) {   // constants replicated across waves: push once
                        const int slot = atomicAdd(&s_wl_cnt, 1);
                        if (slot < WLCAP) {
                            const int j = s_idx[col];
                            s_wl_m[slot] = make_float4(px, py, pz, __int_as_float(p));
                            s_wl_o[slot] = make_float4(nx[p], ny[p], nz[p], 0.0f);
                            s_wl_v[slot] = make_float4(xnb[j*3], xnb[j*3+1], xnb[j*3+2], 0.0f);
                        }
                    }
                }
            }
            // changed-column deltas over this wave's 8-column window
            unsigned wb = (unsigned)((chm >> (wv * 8)) & 0xFFull);
            while (wb) {
                const int bit = __builtin_ctz(wb); wb &= wb - 1;
                const int il  = wv * 8 + bit;
                if ((bm >> il) & 1) continue;
                const float4 c_old = s_xn[il];
                const int    j     = s_idx[c * LPB + il];
                const float4 c_new = make_float4(xnb[j*3], xnb[j*3+1], xnb[j*3+2], 0.0f);
                const float  dp2   = dp2_f(px, py, pz, s_xp[il]);
                #pragma unroll
                for (int p = 0; p < Pn; p++) {
                    if ((chp >> p) & 1) continue;   // handled by worklist
                    d[p] += term2(dp2, nx[p], ny[p], nz[p], c_new)
                          - term2(dp2, nx[p], ny[p], nz[p], c_old);
                }
            }
            #pragma unroll
            for (int p = 0; p < Pn; p++) {
                const float v = wave_sum64(d[p]);
                if (lane == 63) s_part[wv][p] = v;
            }
            // build base mask for group g+2 (other parity slot; current in use)
            if (wv == 3 && g < Gn - 2) {
                if (lane == 0) s_bmask[g & 1] = 0ull;
                const int a2 = autom[(g + 2) * PK + lane];
                const int r  = a2 - c * LPB;
                if (r >= 0 && r < LPB) atomicOr(&s_bmask[g & 1], 1ull << r);
            }
        }
        __syncthreads();   // (C) worklist + colonly partials ready

        // ---- worklist workers: entries x 64 columns, parallel over block ----
        if (hn) {
            const ull chm = s_chm;
            const int nw  = min(s_wl_cnt, WLCAP);
            for (int t = tid; t < nw * 64; t += NTH) {
                const int e = t >> 6, il = t & 63;
                if ((bm >> il) & 1) continue;
                const float4 mm = s_wl_m[e];
                const float4 no = s_wl_o[e];
                const float4 nn = s_wl_v[e];
                const float4 c_old = s_xn[il];
                float4 c_new = c_old;
                if ((chm >> il) & 1) {
                    const int j = s_idx[c * LPB + il];
                    c_new = make_float4(xnb[j*3], xnb[j*3+1], xnb[j*3+2], 0.0f);
                }
                const float dp2 = dp2_f(mm.x, mm.y, mm.z, s_xp[il]);
                const float dt  = term2(dp2, nn.x, nn.y, nn.z, c_new)
                                - term2(dp2, no.x, no.y, no.z, c_old);
                atomicAdd(&s_delta[__float_as_int(mm.w)], dt);
            }
        }
        __syncthreads();   // (D) s_delta complete; s_xn old values consumed

        if (hn) {
            if (wv == 0) {   // publish corrected P_{g+1}
                const float cd = fold8x8(s_part, lane);
                if (lane < 8) {
                    const float tot = sreg + cd + s_delta[lane];
                    ull* pg1 = part + (size_t)((g + 1) * Bn + b) * BPB * Pn;
                    st_rlx64(&pg1[c * Pn + lane],
                             ((ull)MAGIC(g + 1) << 32) | (ull)__float_as_uint(tot));
                }
            }
            if (wv == 1) {   // patch s_xn in place -> map-after-g
                if ((s_chm >> lane) & 1) {
                    const int j = s_idx[c * LPB + lane];
                    s_xn[lane] = make_float4(xnb[j*3], xnb[j*3+1], xnb[j*3+2], 0.0f);
                }
            }
            if (g < Gn - 2) {   // prefetch group g+2 constants (map-after-g)
                const int* ag2 = autom + (g + 2) * PK;
                a0k = ag2[lane];
                px = xpb[a0k*3]; py = xpb[a0k*3+1]; pz = xpb[a0k*3+2];
                #pragma unroll
                for (int p = 0; p < Pn; p++) {
                    const int j = s_idx[ag2[p * Kn + lane]];
                    nx[p] = xnb[j*3]; ny[p] = xnb[j*3+1]; nz[p] = xnb[j*3+2];
                }
            }
        }
        __syncthreads();   // (E) patched s_xn + new constants ready
    }

    // ---- epilogue: out = x_native[idx], mask[idx] ----
    const int l0 = c * LPB;
    if (tid < LPB * 3) {
        const int ll = tid / 3, coord = tid % 3;
        const int l  = l0 + ll;
        const int j  = s_idx[l];
        out_x[((size_t)b * Ln + l) * 3 + coord] = xnb[j * 3 + coord];
    } else if (tid < LPB * 4) {
        const int l = l0 + (tid - LPB * 3);
        const int j = s_idx[l];
        out_m[(size_t)b * Ln + l] = (float)mask_in[(size_t)b * Ln + j];
    }
}

// ---------------------------------------------------------------------------
extern "C" void kernel_launch(void* const* d_in, const int* in_sizes, int n_in,
                              void* d_out, int out_size, void* d_ws, size_t ws_size,
                              hipStream_t stream) {
    const float* xpred   = (const float*)d_in[0];  // (B,L,3) f32
    const float* xnat_in = (const float*)d_in[1];  // (B,L,3) f32
    const int*   mask_in = (const int*)  d_in[2];  // (B,L) bool -> int32
    const int*   autom   = (const int*)  d_in[3];  // (G,P,K) -> int32

    float* out_x = (float*)d_out;          // (B,L,3)
    float* out_m = out_x + Bn * Ln * 3;    // (B,L) as float 0/1

    ull* part = (ull*)d_ws;                // Gn*Bn*BPB*Pn qwords (128KB)

    fused_kernel<<<Bn * BPB, NTH, 0, stream>>>(
        xpred, xnat_in, mask_in, autom, out_x, out_m, part);
}

// Round 12
// 143.115 us; speedup vs baseline: 1.2692x; 1.2692x over previous
//
#include <hip/hip_runtime.h>
#include <math.h>

#define Bn 16
#define Ln 2048
#define Gn 8
#define Pn 8
#define Kn 64
#define CLAMP_V 15.0f

#define BPB 32              // blocks per batch
#define NTH 512             // threads per block = 8 waves
#define NWV (NTH / 64)      // 8 waves
#define LPB (Ln / BPB)      // 64 l's per block
#define LPW (LPB / NWV)     // 8 l's per wave

// Stagger: ~3us in 100MHz s_memrealtime ticks — half of round-10's observed
// per-group period, to push odd (bit-3) batches into anti-phase.
#define STAG_TICKS 300

// d_ws layout: part[Gn][Bn][BPB][Pn] qwords. Each qword = {magic(g) << 32 |
// f32 partial}. Written exactly once per call; harness poison (0xAAAA..)
// never matches a tag, so NO init pass / counter / barrier flag is needed —
// the tagged partial IS the arrival signal (one coherence round trip).

#define MAGIC(g) (0x5EED0000u | (unsigned)(g))

typedef unsigned long long ull;

// wave64 sum via DPP (VALU pipe, no LDS). Total lands in lane 63.
__device__ __forceinline__ float wave_sum64(float x) {
#define DPP_ADD(ctrl) \
    x += __int_as_float(__builtin_amdgcn_update_dpp(0, __float_as_int(x), ctrl, 0xf, 0xf, true))
    DPP_ADD(0x111);  // row_shr:1
    DPP_ADD(0x112);  // row_shr:2
    DPP_ADD(0x114);  // row_shr:4
    DPP_ADD(0x118);  // row_shr:8
    DPP_ADD(0x142);  // row_bcast:15
    DPP_ADD(0x143);  // row_bcast:31
#undef DPP_ADD
    return x;
}

// ds_swizzle pattern must be an integer constant expression -> template param.
template <int IMM>
__device__ __forceinline__ float swz_xor(float v) {
    return v + __int_as_float(__builtin_amdgcn_ds_swizzle(__float_as_int(v), IMM));
}
__device__ __forceinline__ ull ld_rlx64(const ull* p) {
    return __hip_atomic_load(p, __ATOMIC_RELAXED, __HIP_MEMORY_SCOPE_AGENT);
}
__device__ __forceinline__ void st_rlx64(ull* p, ull v) {
    __hip_atomic_store(p, v, __ATOMIC_RELAXED, __HIP_MEMORY_SCOPE_AGENT);
}

// ---------------------------------------------------------------------------
// Round-10 structure (87us kernel, proven) + ONE change: anti-phase kick.
// All 16 independent batch-chains otherwise advance in lock-step (identical
// per-group work), so co-resident blocks compute together and spin together —
// the 40% idle is a globally synchronized wait phase. A one-time ~3us delay
// for batches with bit 3 set (co-resident pair (i,i+256) = batches (b,b+8)
// differ exactly in bit 3 under round-robin dispatch) moves partners into
// anti-phase: each block's publish->observe latency hides under its CU
// partner's compute burst. Cost bounded by the 3us offset if phases realign.
// ---------------------------------------------------------------------------
__global__ __launch_bounds__(NTH, 4) void fused_kernel(
    const float* __restrict__ xpred, const float* __restrict__ xnat,
    const int* __restrict__ mask_in, const int* __restrict__ autom,
    float* __restrict__ out_x, float* __restrict__ out_m,
    ull* __restrict__ part) {

    const int tid  = threadIdx.x;
    const int lane = tid & 63;       // k
    const int wv   = tid >> 6;       // wave 0..7
    const int b    = blockIdx.x >> 5;         // batch
    const int c    = blockIdx.x & (BPB - 1);  // chunk within batch

    __shared__ unsigned short s_idx[Ln];    // 4KB: private permutation
    __shared__ signed char    s_stamp[Ln];  // 2KB: last group that updated row
    __shared__ float4         s_xp[LPB];    // 1KB: x_pred columns, this block
    __shared__ float4         s_xn[2][LPB]; // 2KB: dbuf x_nat columns
    __shared__ float          s_part[NWV][Pn];

    const float* xpb = xpred + (size_t)b * Ln * 3;
    const float* xnb = xnat  + (size_t)b * Ln * 3;

    // ---- prologue ----
    for (int l = tid; l < Ln; l += NTH) {
        s_idx[l]   = (unsigned short)l;
        s_stamp[l] = -1;
    }
    if (wv == 0) {
        const int l = c * LPB + lane;
        s_xp[lane]    = make_float4(xpb[l * 3 + 0], xpb[l * 3 + 1], xpb[l * 3 + 2], 0.0f);
    } else if (wv == 1) {
        const int l = c * LPB + lane;
        s_xn[0][lane] = make_float4(xnb[l * 3 + 0], xnb[l * 3 + 1], xnb[l * 3 + 2], 0.0f);
    }
    int   a0k = autom[lane];
    float px = xpb[a0k * 3 + 0], py = xpb[a0k * 3 + 1], pz = xpb[a0k * 3 + 2];
    float nx[Pn], ny[Pn], nz[Pn];
    #pragma unroll
    for (int p = 0; p < Pn; p++) {
        const int col = autom[p * Kn + lane];   // s_idx identity at g=0
        nx[p] = xnb[col * 3 + 0];
        ny[p] = xnb[col * 3 + 1];
        nz[p] = xnb[col * 3 + 2];
    }

    // ---- anti-phase kick for odd (bit-3) batches, once, before g=0 ----
    if ((b & 8) && wv == 0 && lane == 0) {
        const ull t0 = __builtin_amdgcn_s_memrealtime();   // 100 MHz clock
        while (__builtin_amdgcn_s_memrealtime() - t0 < STAG_TICKS)
            __builtin_amdgcn_s_sleep(8);
    }
    __syncthreads();

    #pragma unroll 1
    for (int g = 0; g < Gn; g++) {
        const int* ag  = autom + g * Pn * Kn;
        const int* ag1 = autom + (g + 1) * Pn * Kn;   // only read when g<7
        const int  cur = g & 1, nxt = cur ^ 1;
        const int  gb  = g * Bn + b;
        ull* pg = part + (size_t)gb * (BPB * Pn);

        // ---- compute: pure VALU inner loop over this wave's l's ----
        float acc[Pn];
        #pragma unroll
        for (int p = 0; p < Pn; p++) acc[p] = 0.0f;

        const int il0 = wv * LPW;
        #pragma unroll 2
        for (int i = 0; i < LPW; i++) {
            const int il = il0 + i;
            const int l  = c * LPB + il;
            if (__ballot(a0k == l)) continue;     // colmask: l in base set (rare)

            const float4 q = s_xp[il];
            const float4 m = s_xn[cur][il];
            const float dx = px - q.x, dy = py - q.y, dz = pz - q.z;
            const float dp2 = dx * dx + dy * dy + dz * dz;

            #pragma unroll
            for (int p = 0; p < Pn; p++) {
                const float ex = nx[p] - m.x, ey = ny[p] - m.y, ez = nz[p] - m.z;
                const float dn2 = ex * ex + ey * ey + ez * ez;
                const float s  = __builtin_amdgcn_sqrtf(dp2 * dn2); // = dp*dn
                const float t  = (dp2 + dn2) - 2.0f * s;            // = (dp-dn)^2
                acc[p] += fminf(t, CLAMP_V);
            }
        }

        // ---- wave reduce (DPP, VALU pipe) ----
        #pragma unroll
        for (int p = 0; p < Pn; p++) {
            const float v = wave_sum64(acc[p]);
            if (lane == 63) s_part[wv][p] = v;
        }
        __syncthreads();

        // ---- wave 0: fold 8 waves x 8 p, publish tagged qwords ASAP ----
        if (wv == 0) {
            float v = s_part[lane >> 3][lane & 7];   // lane = (q<<3)|p
            v = swz_xor<0x201F>(v);                  // fold q bit0 (xor 8)
            v = swz_xor<0x401F>(v);                  // fold q bit1 (xor 16)
            v += __shfl(v, lane + 32, 64);           // fold q bit2 (cross-half)
            if (lane < 8)
                st_rlx64(&pg[c * Pn + lane],
                         ((ull)MAGIC(g) << 32) | (ull)__float_as_uint(v));
        }

        // ---- prefetch next group's state into the SAME registers ----
        if (g < Gn - 1) {
            a0k = ag1[lane];
            px = xpb[a0k * 3 + 0]; py = xpb[a0k * 3 + 1]; pz = xpb[a0k * 3 + 2];
            #pragma unroll
            for (int p = 0; p < Pn; p++) {
                const int j = s_idx[ag1[p * Kn + lane]];   // pre-update map
                nx[p] = xnb[j * 3 + 0];
                ny[p] = xnb[j * 3 + 1];
                nz[p] = xnb[j * 3 + 2];
            }
            if (wv == 1) {
                const int j = s_idx[c * LPB + lane];
                s_xn[nxt][lane] = make_float4(xnb[j * 3 + 0], xnb[j * 3 + 1],
                                              xnb[j * 3 + 2], 0.0f);
            }
        }

        // ---- wave 0: poll all 32x8 tagged qwords (data arrives with flag),
        //      reduce, argmin, permutation update — all register-level ----
        if (wv == 0) {
            const unsigned magic = MAGIC(g);
            ull q0 = 0, q1 = 0, q2 = 0, q3 = 0;
            bool r0 = false, r1 = false, r2 = false, r3 = false;
            for (;;) {
                if (!r0) { q0 = ld_rlx64(pg + lane);       r0 = (unsigned)(q0 >> 32) == magic; }
                if (!r1) { q1 = ld_rlx64(pg + lane + 64);  r1 = (unsigned)(q1 >> 32) == magic; }
                if (!r2) { q2 = ld_rlx64(pg + lane + 128); r2 = (unsigned)(q2 >> 32) == magic; }
                if (!r3) { q3 = ld_rlx64(pg + lane + 192); r3 = (unsigned)(q3 >> 32) == magic; }
                if (__ballot(!(r0 && r1 && r2 && r3)) == 0ull) break;
                __builtin_amdgcn_s_sleep(1);
            }
            float v = __uint_as_float((unsigned)q0) + __uint_as_float((unsigned)q1)
                    + __uint_as_float((unsigned)q2) + __uint_as_float((unsigned)q3);
            v = swz_xor<0x201F>(v);          // fold c bit (lane bit 3)
            v = swz_xor<0x401F>(v);          // fold c bit (lane bit 4)
            v += __shfl(v, lane + 32, 64);   // fold c bit (lane bit 5)
            // lanes 0..7 hold total drms[p = lane]; argmin uniform via shfl
            float best = __shfl(v, 0, 64);
            int   bj   = 0;
            #pragma unroll
            for (int p = 1; p < Pn; p++) {
                const float t = __shfl(v, p, 64);
                if (t < best) { best = t; bj = p; }  // strict < == argmin tie rule
            }
            // permutation update (gather then scatter, in-wave DS order)
            const unsigned short oldv = s_idx[ag[bj * Kn + lane]];
            s_idx[ag[lane]]   = oldv;
            s_stamp[ag[lane]] = (signed char)g;
        }
        __syncthreads();

        // ---- patch prefetched state where this group's update changed rows ----
        if (g < Gn - 1) {
            #pragma unroll
            for (int p = 0; p < Pn; p++) {
                const int col = ag1[p * Kn + lane];       // L1-hot reload
                if (s_stamp[col] == (signed char)g) {
                    const int j = s_idx[col];
                    nx[p] = xnb[j * 3 + 0];
                    ny[p] = xnb[j * 3 + 1];
                    nz[p] = xnb[j * 3 + 2];
                }
            }
            if (wv == 1) {
                const int l = c * LPB + lane;
                if (s_stamp[l] == (signed char)g) {
                    const int j = s_idx[l];
                    s_xn[nxt][lane] = make_float4(xnb[j * 3 + 0], xnb[j * 3 + 1],
                                                  xnb[j * 3 + 2], 0.0f);
                }
            }
            __syncthreads();   // s_xn[nxt] visible before next compute
        }
    }

    // ---- epilogue: out = x_native[idx], mask[idx] ----
    const int l0 = c * LPB;
    if (tid < LPB * 3) {
        const int ll = tid / 3, coord = tid % 3;
        const int l  = l0 + ll;
        const int j  = s_idx[l];
        out_x[((size_t)b * Ln + l) * 3 + coord] = xnb[j * 3 + coord];
    } else if (tid < LPB * 4) {
        const int l = l0 + (tid - LPB * 3);
        const int j = s_idx[l];
        out_m[(size_t)b * Ln + l] = (float)mask_in[(size_t)b * Ln + j];
    }
}

// ---------------------------------------------------------------------------
extern "C" void kernel_launch(void* const* d_in, const int* in_sizes, int n_in,
                              void* d_out, int out_size, void* d_ws, size_t ws_size,
                              hipStream_t stream) {
    const float* xpred   = (const float*)d_in[0];  // (B,L,3) f32
    const float* xnat_in = (const float*)d_in[1];  // (B,L,3) f32
    const int*   mask_in = (const int*)  d_in[2];  // (B,L) bool -> int32
    const int*   autom   = (const int*)  d_in[3];  // (G,P,K) -> int32

    float* out_x = (float*)d_out;          // (B,L,3)
    float* out_m = out_x + Bn * Ln * 3;    // (B,L) as float 0/1

    ull* part = (ull*)d_ws;                // Gn*Bn*BPB*Pn qwords (128KB)

    fused_kernel<<<Bn * BPB, NTH, 0, stream>>>(
        xpred, xnat_in, mask_in, autom, out_x, out_m, part);
}

// Round 13
// 134.816 us; speedup vs baseline: 1.3474x; 1.0616x over previous
//
#include <hip/hip_runtime.h>
#include <math.h>

#define Bn 16
#define Ln 2048
#define Gn 8
#define Pn 8
#define Kn 64
#define CLAMP_V 15.0f

#define BPB 32              // blocks per batch
#define NTH 512             // threads per block = 8 waves
#define NWV (NTH / 64)      // 8 waves
#define LPB (Ln / BPB)      // 64 l's per block
#define LPW (LPB / NWV)     // 8 l's per wave

// d_ws layout: part[Gn][Bn][BPB][Pn] qwords = {MAGIC(g)<<32 | f32 partial}.
// Harness 0xAA poison never matches a tag -> tagged partial IS the arrival
// signal; no init pass, no counters (round-10-proven protocol).
#define MAGIC(g) (0x5EED0000u | (unsigned)(g))

typedef unsigned long long ull;

// wave64 sum via DPP (VALU pipe, no LDS). Total lands in lane 63.
__device__ __forceinline__ float wave_sum64(float x) {
#define DPP_ADD(ctrl) \
    x += __int_as_float(__builtin_amdgcn_update_dpp(0, __float_as_int(x), ctrl, 0xf, 0xf, true))
    DPP_ADD(0x111);  // row_shr:1
    DPP_ADD(0x112);  // row_shr:2
    DPP_ADD(0x114);  // row_shr:4
    DPP_ADD(0x118);  // row_shr:8
    DPP_ADD(0x142);  // row_bcast:15
    DPP_ADD(0x143);  // row_bcast:31
#undef DPP_ADD
    return x;
}

// ds_swizzle pattern must be an integer constant expression -> template param.
template <int IMM>
__device__ __forceinline__ float swz_xor(float v) {
    return v + __int_as_float(__builtin_amdgcn_ds_swizzle(__float_as_int(v), IMM));
}
__device__ __forceinline__ ull ld_rlx64(const ull* p) {
    return __hip_atomic_load(p, __ATOMIC_RELAXED, __HIP_MEMORY_SCOPE_AGENT);
}
__device__ __forceinline__ void st_rlx64(ull* p, ull v) {
    __hip_atomic_store(p, v, __ATOMIC_RELAXED, __HIP_MEMORY_SCOPE_AGENT);
}

// ---------------------------------------------------------------------------
// Round-10 structure (87us kernel, proven; round-12 stagger kick REVERTED —
// it regressed 87->94) + ONE change: the whole batch x_nat (2048 x float4 =
// 32KB) lives in LDS per block. All per-group permuted gathers (8x3 lane
// constants, s_xn staging, patch, epilogue) become ds_read instead of ~25
// scattered 4B global loads per thread per group — removing the L2 gather
// storm whose latency tail (200-900cyc x thousands of misses) sat between
// the barriers and set the publish skew. LDS 41KB/block -> 3 blocks/CU
// capacity >= 2 needed for co-residency (slack preserved).
// ---------------------------------------------------------------------------
__global__ __launch_bounds__(NTH, 2) void fused_kernel(
    const float* __restrict__ xpred, const float* __restrict__ xnat,
    const int* __restrict__ mask_in, const int* __restrict__ autom,
    float* __restrict__ out_x, float* __restrict__ out_m,
    ull* __restrict__ part) {

    const int tid  = threadIdx.x;
    const int lane = tid & 63;       // k
    const int wv   = tid >> 6;       // wave 0..7
    const int b    = blockIdx.x >> 5;         // batch
    const int c    = blockIdx.x & (BPB - 1);  // chunk within batch

    __shared__ float4         s_all[Ln];    // 32KB: entire batch x_nat rows
    __shared__ unsigned short s_idx[Ln];    // 4KB: private permutation
    __shared__ signed char    s_stamp[Ln];  // 2KB: last group that updated row
    __shared__ float4         s_xp[LPB];    // 1KB: x_pred columns, this block
    __shared__ float4         s_xn[2][LPB]; // 2KB: dbuf x_nat columns
    __shared__ float          s_part[NWV][Pn];

    const float* xpb = xpred + (size_t)b * Ln * 3;
    const float* xnb = xnat  + (size_t)b * Ln * 3;

    // ---- prologue: stage whole-batch x_nat into LDS (coalesced, once) ----
    for (int l = tid; l < Ln; l += NTH) {
        s_idx[l]   = (unsigned short)l;
        s_stamp[l] = -1;
        s_all[l]   = make_float4(xnb[l * 3 + 0], xnb[l * 3 + 1], xnb[l * 3 + 2], 0.0f);
    }
    if (wv == 0) {
        const int l = c * LPB + lane;
        s_xp[lane] = make_float4(xpb[l * 3 + 0], xpb[l * 3 + 1], xpb[l * 3 + 2], 0.0f);
    }
    int   a0k = autom[lane];
    float px = xpb[a0k * 3 + 0], py = xpb[a0k * 3 + 1], pz = xpb[a0k * 3 + 2];
    __syncthreads();   // s_all ready before any permuted read
    if (wv == 1) {
        const int l = c * LPB + lane;
        s_xn[0][lane] = s_all[l];
    }
    float nx[Pn], ny[Pn], nz[Pn];
    #pragma unroll
    for (int p = 0; p < Pn; p++) {
        const int col = autom[p * Kn + lane];   // s_idx identity at g=0
        const float4 v = s_all[col];
        nx[p] = v.x; ny[p] = v.y; nz[p] = v.z;
    }
    __syncthreads();

    #pragma unroll 1
    for (int g = 0; g < Gn; g++) {
        const int* ag  = autom + g * Pn * Kn;
        const int* ag1 = autom + (g + 1) * Pn * Kn;   // only read when g<7
        const int  cur = g & 1, nxt = cur ^ 1;
        const int  gb  = g * Bn + b;
        ull* pg = part + (size_t)gb * (BPB * Pn);

        // ---- compute: pure VALU inner loop over this wave's l's ----
        float acc[Pn];
        #pragma unroll
        for (int p = 0; p < Pn; p++) acc[p] = 0.0f;

        const int il0 = wv * LPW;
        #pragma unroll 2
        for (int i = 0; i < LPW; i++) {
            const int il = il0 + i;
            const int l  = c * LPB + il;
            if (__ballot(a0k == l)) continue;     // colmask: l in base set (rare)

            const float4 q = s_xp[il];
            const float4 m = s_xn[cur][il];
            const float dx = px - q.x, dy = py - q.y, dz = pz - q.z;
            const float dp2 = dx * dx + dy * dy + dz * dz;

            #pragma unroll
            for (int p = 0; p < Pn; p++) {
                const float ex = nx[p] - m.x, ey = ny[p] - m.y, ez = nz[p] - m.z;
                const float dn2 = ex * ex + ey * ey + ez * ez;
                const float s  = __builtin_amdgcn_sqrtf(dp2 * dn2); // = dp*dn
                const float t  = (dp2 + dn2) - 2.0f * s;            // = (dp-dn)^2
                acc[p] += fminf(t, CLAMP_V);
            }
        }

        // ---- wave reduce (DPP, VALU pipe) ----
        #pragma unroll
        for (int p = 0; p < Pn; p++) {
            const float v = wave_sum64(acc[p]);
            if (lane == 63) s_part[wv][p] = v;
        }
        __syncthreads();

        // ---- wave 0: fold 8 waves x 8 p, publish tagged qwords ASAP ----
        if (wv == 0) {
            float v = s_part[lane >> 3][lane & 7];   // lane = (q<<3)|p
            v = swz_xor<0x201F>(v);                  // fold q bit0 (xor 8)
            v = swz_xor<0x401F>(v);                  // fold q bit1 (xor 16)
            v += __shfl(v, lane + 32, 64);           // fold q bit2 (cross-half)
            if (lane < 8)
                st_rlx64(&pg[c * Pn + lane],
                         ((ull)MAGIC(g) << 32) | (ull)__float_as_uint(v));
        }

        // ---- prefetch next group's state (LDS gathers, no global storm) ----
        if (g < Gn - 1) {
            a0k = ag1[lane];
            px = xpb[a0k * 3 + 0]; py = xpb[a0k * 3 + 1]; pz = xpb[a0k * 3 + 2];
            #pragma unroll
            for (int p = 0; p < Pn; p++) {
                const float4 v = s_all[s_idx[ag1[p * Kn + lane]]];  // pre-update map
                nx[p] = v.x; ny[p] = v.y; nz[p] = v.z;
            }
            if (wv == 1) {
                s_xn[nxt][lane] = s_all[s_idx[c * LPB + lane]];
            }
        }

        // ---- wave 0: poll all 32x8 tagged qwords (data arrives with flag),
        //      reduce, argmin, permutation update — all register-level ----
        if (wv == 0) {
            const unsigned magic = MAGIC(g);
            ull q0 = 0, q1 = 0, q2 = 0, q3 = 0;
            bool r0 = false, r1 = false, r2 = false, r3 = false;
            for (;;) {
                if (!r0) { q0 = ld_rlx64(pg + lane);       r0 = (unsigned)(q0 >> 32) == magic; }
                if (!r1) { q1 = ld_rlx64(pg + lane + 64);  r1 = (unsigned)(q1 >> 32) == magic; }
                if (!r2) { q2 = ld_rlx64(pg + lane + 128); r2 = (unsigned)(q2 >> 32) == magic; }
                if (!r3) { q3 = ld_rlx64(pg + lane + 192); r3 = (unsigned)(q3 >> 32) == magic; }
                if (__ballot(!(r0 && r1 && r2 && r3)) == 0ull) break;
                __builtin_amdgcn_s_sleep(1);
            }
            float v = __uint_as_float((unsigned)q0) + __uint_as_float((unsigned)q1)
                    + __uint_as_float((unsigned)q2) + __uint_as_float((unsigned)q3);
            v = swz_xor<0x201F>(v);          // fold c bit (lane bit 3)
            v = swz_xor<0x401F>(v);          // fold c bit (lane bit 4)
            v += __shfl(v, lane + 32, 64);   // fold c bit (lane bit 5)
            // lanes 0..7 hold total drms[p = lane]; argmin uniform via shfl
            float best = __shfl(v, 0, 64);
            int   bj   = 0;
            #pragma unroll
            for (int p = 1; p < Pn; p++) {
                const float t = __shfl(v, p, 64);
                if (t < best) { best = t; bj = p; }  // strict < == argmin tie rule
            }
            // permutation update (gather then scatter, in-wave DS order)
            const unsigned short oldv = s_idx[ag[bj * Kn + lane]];
            s_idx[ag[lane]]   = oldv;
            s_stamp[ag[lane]] = (signed char)g;
        }
        __syncthreads();

        // ---- patch prefetched state where this group's update changed rows ----
        if (g < Gn - 1) {
            #pragma unroll
            for (int p = 0; p < Pn; p++) {
                const int col = ag1[p * Kn + lane];       // L1-hot reload
                if (s_stamp[col] == (signed char)g) {
                    const float4 v = s_all[s_idx[col]];
                    nx[p] = v.x; ny[p] = v.y; nz[p] = v.z;
                }
            }
            if (wv == 1) {
                const int l = c * LPB + lane;
                if (s_stamp[l] == (signed char)g) {
                    s_xn[nxt][lane] = s_all[s_idx[l]];
                }
            }
            __syncthreads();   // s_xn[nxt] visible before next compute
        }
    }

    // ---- epilogue: out = x_native[idx] (from LDS), mask[idx] ----
    const int l0 = c * LPB;
    if (tid < LPB * 3) {
        const int ll = tid / 3, coord = tid % 3;
        const int l  = l0 + ll;
        const float4 v = s_all[s_idx[l]];
        out_x[((size_t)b * Ln + l) * 3 + coord] =
            (coord == 0) ? v.x : ((coord == 1) ? v.y : v.z);
    } else if (tid < LPB * 4) {
        const int l = l0 + (tid - LPB * 3);
        const int j = s_idx[l];
        out_m[(size_t)b * Ln + l] = (float)mask_in[(size_t)b * Ln + j];
    }
}

// ---------------------------------------------------------------------------
extern "C" void kernel_launch(void* const* d_in, const int* in_sizes, int n_in,
                              void* d_out, int out_size, void* d_ws, size_t ws_size,
                              hipStream_t stream) {
    const float* xpred   = (const float*)d_in[0];  // (B,L,3) f32
    const float* xnat_in = (const float*)d_in[1];  // (B,L,3) f32
    const int*   mask_in = (const int*)  d_in[2];  // (B,L) bool -> int32
    const int*   autom   = (const int*)  d_in[3];  // (G,P,K) -> int32

    float* out_x = (float*)d_out;          // (B,L,3)
    float* out_m = out_x + Bn * Ln * 3;    // (B,L) as float 0/1

    ull* part = (ull*)d_ws;                // Gn*Bn*BPB*Pn qwords (128KB)

    fused_kernel<<<Bn * BPB, NTH, 0, stream>>>(
        xpred, xnat_in, mask_in, autom, out_x, out_m, part);
}

// Round 14
// 116.357 us; speedup vs baseline: 1.5611x; 1.1586x over previous
//
#include <hip/hip_runtime.h>
#include <math.h>

#define Bn 16
#define Ln 2048
#define Gn 8
#define Pn 8
#define Kn 64
#define CLAMP_V 15.0f

#define BPB 32              // blocks per batch
#define NTH 512             // threads per block = 8 waves
#define NWV (NTH / 64)      // 8 waves
#define LPB (Ln / BPB)      // 64 l's per block
#define LPW (LPB / NWV)     // 8 l's per wave
#define PK  (Pn * Kn)

// d_ws: part[Gn][Bn][BPB][Pn] qwords = {MAGIC(g)<<32 | f32 partial}.
// Harness 0xAA poison never matches a tag -> tagged partial IS the arrival
// signal; no init pass, no counters (round-10-proven protocol).
#define MAGIC(g) (0x5EED0000u | (unsigned)(g))

typedef unsigned long long ull;

// wave64 sum via DPP (VALU pipe, no LDS). Total lands in lane 63.
__device__ __forceinline__ float wave_sum64(float x) {
#define DPP_ADD(ctrl) \
    x += __int_as_float(__builtin_amdgcn_update_dpp(0, __float_as_int(x), ctrl, 0xf, 0xf, true))
    DPP_ADD(0x111);  // row_shr:1
    DPP_ADD(0x112);  // row_shr:2
    DPP_ADD(0x114);  // row_shr:4
    DPP_ADD(0x118);  // row_shr:8
    DPP_ADD(0x142);  // row_bcast:15
    DPP_ADD(0x143);  // row_bcast:31
#undef DPP_ADD
    return x;
}

template <int IMM>
__device__ __forceinline__ float swz_xor(float v) {
    return v + __int_as_float(__builtin_amdgcn_ds_swizzle(__float_as_int(v), IMM));
}
__device__ __forceinline__ ull ld_rlx64(const ull* p) {
    return __hip_atomic_load(p, __ATOMIC_RELAXED, __HIP_MEMORY_SCOPE_AGENT);
}
__device__ __forceinline__ void st_rlx64(ull* p, ull v) {
    __hip_atomic_store(p, v, __ATOMIC_RELAXED, __HIP_MEMORY_SCOPE_AGENT);
}

// ---------------------------------------------------------------------------
// Round-13 sync protocol (tagged-qword publish/poll, proven) + dn-sharing:
// dn(node j, l) is computed ONCE per (j,l) — lane j holds base-position j's
// pred point and current native point; per p, the permuted dn reaches lane k
// via ONE ds_bpermute with a static byte-address sig[p] = 4*inv_g(a[p][k])
// (inv tables in LDS, double-buffered per group parity). Inner (k,l) cost:
// ~98 VALU + 8 sqrt  ->  ~50 VALU + 2 sqrt + 8 bperm (LDS pipe, mostly idle).
// r4's 122us "failure" of this loop was its 3-round-trip sync, not the bperm.
// Also deleted: s_xn staging/patch/stamp — the inner loop reads
// s_all[s_idx[l]] directly (updates are barrier-separated from compute);
// 2 barriers/group instead of 3.
// ---------------------------------------------------------------------------
__global__ __launch_bounds__(NTH, 2) void fused_kernel(
    const float* __restrict__ xpred, const float* __restrict__ xnat,
    const int* __restrict__ mask_in, const int* __restrict__ autom,
    float* __restrict__ out_x, float* __restrict__ out_m,
    ull* __restrict__ part) {

    const int tid  = threadIdx.x;
    const int lane = tid & 63;       // k = base position
    const int wv   = tid >> 6;       // wave 0..7
    const int b    = blockIdx.x >> 5;         // batch
    const int c    = blockIdx.x & (BPB - 1);  // chunk within batch

    __shared__ float4         s_all[Ln];      // 32KB: whole-batch x_nat rows
    __shared__ unsigned short s_idx[Ln];      // 4KB: private permutation
    __shared__ unsigned char  s_inv[2][Ln];   // 4KB: node -> base position
    __shared__ float4         s_xp[LPB];      // 1KB: x_pred cols, this block
    __shared__ float          s_part[NWV][Pn];

    const float* xpb = xpred + (size_t)b * Ln * 3;
    const float* xnb = xnat  + (size_t)b * Ln * 3;

    // ---- prologue ----
    for (int l = tid; l < Ln; l += NTH) {
        s_idx[l] = (unsigned short)l;
        s_all[l] = make_float4(xnb[l * 3 + 0], xnb[l * 3 + 1], xnb[l * 3 + 2], 0.0f);
    }
    if (wv == 0) {
        const int l = c * LPB + lane;
        s_xp[lane] = make_float4(xpb[l * 3 + 0], xpb[l * 3 + 1], xpb[l * 3 + 2], 0.0f);
    } else if (wv == 2) {
        s_inv[0][autom[lane]] = (unsigned char)lane;   // group-0 inverse map
    }
    int   a0k = autom[lane];                 // group-0 base node of this lane
    float px = xpb[a0k * 3 + 0], py = xpb[a0k * 3 + 1], pz = xpb[a0k * 3 + 2];
    __syncthreads();

    #pragma unroll 1
    for (int g = 0; g < Gn; g++) {
        const int* ag  = autom + g * PK;
        const int* ag1 = autom + (g + 1) * PK;   // only read when g<7
        const int  cur = g & 1, nxt = cur ^ 1;
        ull* pg = part + (size_t)(g * Bn + b) * (BPB * Pn);

        // ---- per-group lane constants (post-update-(g-1) map) ----
        const float4 nk = s_all[s_idx[a0k]];     // native point of base pos k
        int sig[Pn];                             // bpermute byte addresses
        #pragma unroll
        for (int p = 0; p < Pn; p++)
            sig[p] = 4 * (int)s_inv[cur][ag[p * Kn + lane]];
        unsigned short jl[LPW];                  // hoisted column row-ids
        #pragma unroll
        for (int i = 0; i < LPW; i++)
            jl[i] = s_idx[c * LPB + wv * LPW + i];

        float acc[Pn];
        #pragma unroll
        for (int p = 0; p < Pn; p++) acc[p] = 0.0f;

        // ---- compute: dn shared across the 8 perms via bpermute ----
        #pragma unroll 2
        for (int i = 0; i < LPW; i++) {
            const int il = wv * LPW + i;
            const int l  = c * LPB + il;
            if (__ballot(a0k == l)) continue;    // colmask: l in base set (rare)

            const float4 q = s_xp[il];
            const float4 m = s_all[jl[i]];
            const float dx = px - q.x, dy = py - q.y, dz = pz - q.z;
            const float dp = __builtin_amdgcn_sqrtf(dx * dx + dy * dy + dz * dz);
            const float ex = nk.x - m.x, ey = nk.y - m.y, ez = nk.z - m.z;
            const float dn = __builtin_amdgcn_sqrtf(ex * ex + ey * ey + ez * ez);

            #pragma unroll
            for (int p = 0; p < Pn; p++) {
                const float dns = __int_as_float(
                    __builtin_amdgcn_ds_bpermute(sig[p], __float_as_int(dn)));
                const float e = dp - dns;
                acc[p] += fminf(e * e, CLAMP_V);
            }
        }

        // ---- wave reduce (DPP, VALU pipe) ----
        #pragma unroll
        for (int p = 0; p < Pn; p++) {
            const float v = wave_sum64(acc[p]);
            if (lane == 63) s_part[wv][p] = v;
        }
        __syncthreads();   // (A) s_part complete; compute done block-wide

        // ---- wave 0: fold 8 waves x 8 p, publish tagged qwords ASAP ----
        if (wv == 0) {
            float v = s_part[lane >> 3][lane & 7];   // lane = (q<<3)|p
            v = swz_xor<0x201F>(v);                  // fold q bit0 (xor 8)
            v = swz_xor<0x401F>(v);                  // fold q bit1 (xor 16)
            v += __shfl(v, lane + 32, 64);           // fold q bit2 (cross-half)
            if (lane < 8)
                st_rlx64(&pg[c * Pn + lane],
                         ((ull)MAGIC(g) << 32) | (ull)__float_as_uint(v));
        }

        // ---- prefetch next group's static state ----
        if (g < Gn - 1) {
            a0k = ag1[lane];
            px = xpb[a0k * 3 + 0]; py = xpb[a0k * 3 + 1]; pz = xpb[a0k * 3 + 2];
            if (wv == 2) s_inv[nxt][ag1[lane]] = (unsigned char)lane;
        }

        // ---- wave 0: poll tagged qwords, reduce, argmin, update s_idx ----
        if (wv == 0) {
            const unsigned magic = MAGIC(g);
            ull q0 = 0, q1 = 0, q2 = 0, q3 = 0;
            bool r0 = false, r1 = false, r2 = false, r3 = false;
            for (;;) {
                if (!r0) { q0 = ld_rlx64(pg + lane);       r0 = (unsigned)(q0 >> 32) == magic; }
                if (!r1) { q1 = ld_rlx64(pg + lane + 64);  r1 = (unsigned)(q1 >> 32) == magic; }
                if (!r2) { q2 = ld_rlx64(pg + lane + 128); r2 = (unsigned)(q2 >> 32) == magic; }
                if (!r3) { q3 = ld_rlx64(pg + lane + 192); r3 = (unsigned)(q3 >> 32) == magic; }
                if (__ballot(!(r0 && r1 && r2 && r3)) == 0ull) break;
                __builtin_amdgcn_s_sleep(1);
            }
            float v = __uint_as_float((unsigned)q0) + __uint_as_float((unsigned)q1)
                    + __uint_as_float((unsigned)q2) + __uint_as_float((unsigned)q3);
            v = swz_xor<0x201F>(v);          // fold c bit (lane bit 3)
            v = swz_xor<0x401F>(v);          // fold c bit (lane bit 4)
            v += __shfl(v, lane + 32, 64);   // fold c bit (lane bit 5)
            // lanes 0..7 hold total drms[p = lane]; argmin uniform via shfl
            float best = __shfl(v, 0, 64);
            int   bj   = 0;
            #pragma unroll
            for (int p = 1; p < Pn; p++) {
                const float t = __shfl(v, p, 64);
                if (t < best) { best = t; bj = p; }  // strict < == argmin tie rule
            }
            // permutation update (gather then scatter, in-wave DS order)
            const unsigned short oldv = s_idx[ag[bj * Kn + lane]];
            s_idx[ag[lane]] = oldv;
        }
        __syncthreads();   // (B) s_idx + s_inv[nxt] visible for next compute
    }

    // ---- epilogue: out = x_native[idx] (from LDS), mask[idx] ----
    const int l0 = c * LPB;
    if (tid < LPB * 3) {
        const int ll = tid / 3, coord = tid % 3;
        const int l  = l0 + ll;
        const float4 v = s_all[s_idx[l]];
        out_x[((size_t)b * Ln + l) * 3 + coord] =
            (coord == 0) ? v.x : ((coord == 1) ? v.y : v.z);
    } else if (tid < LPB * 4) {
        const int l = l0 + (tid - LPB * 3);
        const int j = s_idx[l];
        out_m[(size_t)b * Ln + l] = (float)mask_in[(size_t)b * Ln + j];
    }
}

// ---------------------------------------------------------------------------
extern "C" void kernel_launch(void* const* d_in, const int* in_sizes, int n_in,
                              void* d_out, int out_size, void* d_ws, size_t ws_size,
                              hipStream_t stream) {
    const float* xpred   = (const float*)d_in[0];  // (B,L,3) f32
    const float* xnat_in = (const float*)d_in[1];  // (B,L,3) f32
    const int*   mask_in = (const int*)  d_in[2];  // (B,L) bool -> int32
    const int*   autom   = (const int*)  d_in[3];  // (G,P,K) -> int32

    float* out_x = (float*)d_out;          // (B,L,3)
    float* out_m = out_x + Bn * Ln * 3;    // (B,L) as float 0/1

    ull* part = (ull*)d_ws;                // Gn*Bn*BPB*Pn qwords (256KB)

    fused_kernel<<<Bn * BPB, NTH, 0, stream>>>(
        xpred, xnat_in, mask_in, autom, out_x, out_m, part);
}